// Round 1
// baseline (263.101 us; speedup 1.0000x reference)
//
#include <hip/hip_runtime.h>
#include <hip/hip_bf16.h>

typedef unsigned short u16;
typedef __bf16 bf16x8 __attribute__((ext_vector_type(8)));
typedef float f32x4 __attribute__((ext_vector_type(4)));

#define QSCALE (0.125f * 1.44269504088896340736f)   // hd^-0.5 * log2(e), folded into Q

__device__ __forceinline__ u16 f2bf(float f) {
    __hip_bfloat16 h = __float2bfloat16(f);
    return __builtin_bit_cast(u16, h);
}
__device__ __forceinline__ float bf2f(u16 u) {
    unsigned int x = ((unsigned int)u) << 16;
    return __builtin_bit_cast(float, x);
}
__device__ __forceinline__ bf16x8 ld_bf8(const u16* p) {
    uint4 u = *reinterpret_cast<const uint4*>(p);
    return __builtin_bit_cast(bf16x8, u);
}

// ---------------------------------------------------------------- prep ----
// Convert x, qkv_w, proj_w to bf16; compute logts[b][l] = log2(max(ts,1e-8))
// (or -1e30 if key_padding_mask).
__global__ __launch_bounds__(256) void prep_kernel(
    const float* __restrict__ x, const float* __restrict__ qkvw,
    const float* __restrict__ projw, const float* __restrict__ ts,
    const unsigned char* __restrict__ kpm,
    u16* __restrict__ Xb, u16* __restrict__ Wq, u16* __restrict__ Wp,
    float* __restrict__ logts)
{
    int i = blockIdx.x * 256 + threadIdx.x;
    const int XC = 4096 * 768;
    const int WQ = 2304 * 768;
    const int WP = 768 * 768;
    if (i < XC) { Xb[i] = f2bf(x[i]); return; }
    i -= XC;
    if (i < WQ) { Wq[i] = f2bf(qkvw[i]); return; }
    i -= WQ;
    if (i < WP) { Wp[i] = f2bf(projw[i]); return; }
    i -= WP;
    if (i < 2 * 2048) {
        float t = ts[i];
        logts[i] = (kpm[i] != 0) ? -1e30f : log2f(fmaxf(t, 1e-8f));
    }
}

// ---------------------------------------------------------------- GEMM ----
// C[m][n] = sum_k A[m][k] * Bm[n][k] (+bias). 128x128 tile, BK=32, 4 waves.
// EPI==0: scatter to Q (scaled), K, V^T (bf16).  EPI==1: f32 out.
template<int EPI>
__global__ __launch_bounds__(256) void gemm_bt(
    const u16* __restrict__ A, const u16* __restrict__ Bm,
    const float* __restrict__ bias,
    u16* __restrict__ Qb, u16* __restrict__ Kb, u16* __restrict__ Vt,
    float* __restrict__ outp)
{
    __shared__ u16 As[128][40];   // +8 pad: 2-way LDS conflicts only (free)
    __shared__ u16 Bs[128][40];
    const int K = 768;
    const int tid = threadIdx.x;
    const int m0 = blockIdx.y * 128;
    const int n0 = blockIdx.x * 128;
    const int w = tid >> 6, lane = tid & 63;
    const int wr = (w >> 1) * 64, wc = (w & 1) * 64;
    const int g = lane >> 4, l16 = lane & 15;

    const int lrow = tid >> 1;
    const int lcol = (tid & 1) * 16;
    const u16* gA = A + (size_t)(m0 + lrow) * K + lcol;
    const u16* gB = Bm + (size_t)(n0 + lrow) * K + lcol;

    f32x4 acc[4][4] = {};
    for (int k0 = 0; k0 < K; k0 += 32) {
        uint4 a0 = *(const uint4*)(gA + k0);
        uint4 a1 = *(const uint4*)(gA + k0 + 8);
        uint4 b0 = *(const uint4*)(gB + k0);
        uint4 b1 = *(const uint4*)(gB + k0 + 8);
        __syncthreads();
        *(uint4*)&As[lrow][lcol]     = a0;
        *(uint4*)&As[lrow][lcol + 8] = a1;
        *(uint4*)&Bs[lrow][lcol]     = b0;
        *(uint4*)&Bs[lrow][lcol + 8] = b1;
        __syncthreads();
        bf16x8 af[4], bfr[4];
        #pragma unroll
        for (int i = 0; i < 4; i++) af[i]  = ld_bf8(&As[wr + i*16 + l16][g*8]);
        #pragma unroll
        for (int j = 0; j < 4; j++) bfr[j] = ld_bf8(&Bs[wc + j*16 + l16][g*8]);
        #pragma unroll
        for (int i = 0; i < 4; i++)
            #pragma unroll
            for (int j = 0; j < 4; j++)
                acc[i][j] = __builtin_amdgcn_mfma_f32_16x16x32_bf16(af[i], bfr[j], acc[i][j], 0, 0, 0);
    }

    #pragma unroll
    for (int j = 0; j < 4; j++) {
        const int n = n0 + wc + j*16 + l16;
        const float bs = bias[n];
        #pragma unroll
        for (int i = 0; i < 4; i++) {
            #pragma unroll
            for (int r = 0; r < 4; r++) {
                const int m = m0 + wr + i*16 + g*4 + r;   // C/D: row=(lane>>4)*4+reg, col=lane&15
                float v = acc[i][j][r] + bs;
                if (EPI == 0) {
                    int b = m >> 11, l = m & 2047;
                    unsigned int which = (unsigned int)n / 768u;
                    int rem = n - (int)which * 768;
                    int h = rem >> 6, d = rem & 63;
                    int bh = b * 12 + h;
                    if (which == 0)      Qb[((size_t)bh*2048 + l)*64 + d] = f2bf(v * QSCALE);
                    else if (which == 1) Kb[((size_t)bh*2048 + l)*64 + d] = f2bf(v);
                    else                 Vt[((size_t)bh*64 + d)*2048 + l] = f2bf(v);
                } else {
                    outp[(size_t)m * 768 + n] = v;
                }
            }
        }
    }
}

// ----------------------------------------------------------- attention ----
// Flash-style causal attention. Block = 4 waves; each wave owns 16 q-rows.
// Key tile = 64. Base-2 softmax (scale*log2e folded into Q; log2(ts) bias).
__global__ __launch_bounds__(256) void attn_kernel(
    const u16* __restrict__ Q, const u16* __restrict__ Kb,
    const u16* __restrict__ Vt, const float* __restrict__ logts,
    u16* __restrict__ O)
{
    __shared__ u16 P[4][16][72];   // wave-private P tiles, padded stride
    const int w = threadIdx.x >> 6, lane = threadIdx.x & 63;
    const int g = lane >> 4, l16 = lane & 15;
    const int qt = blockIdx.x;     // 0..31
    const int bh = blockIdx.y;     // 0..23
    const int b = bh / 12, h = bh - b * 12;
    const int q0 = qt * 64 + w * 16;

    const u16* Qp = Q + ((size_t)bh * 2048 + q0) * 64;
    const u16* Kp = Kb + (size_t)bh * 2048 * 64;
    const u16* Vp = Vt + (size_t)bh * 64 * 2048;
    const float* lt = logts + b * 2048;

    bf16x8 qf0 = ld_bf8(Qp + l16 * 64 + g * 8);
    bf16x8 qf1 = ld_bf8(Qp + l16 * 64 + 32 + g * 8);

    f32x4 o[4] = {};
    float mrow[4], lrow[4];
    #pragma unroll
    for (int r = 0; r < 4; r++) { mrow[r] = -1e30f; lrow[r] = 0.f; }
    const int qrow_my = q0 + g * 4;   // +r

    for (int kt = 0; kt <= qt; kt++) {
        const int k0 = kt * 64;
        // ---- S = Q·K^T (4 key sub-tiles of 16) ----
        f32x4 s[4];
        #pragma unroll
        for (int t = 0; t < 4; t++) {
            const u16* kp = Kp + (size_t)(k0 + t*16 + l16) * 64 + g * 8;
            bf16x8 kf0 = ld_bf8(kp);
            bf16x8 kf1 = ld_bf8(kp + 32);
            f32x4 z = {};
            z = __builtin_amdgcn_mfma_f32_16x16x32_bf16(qf0, kf0, z, 0, 0, 0);
            z = __builtin_amdgcn_mfma_f32_16x16x32_bf16(qf1, kf1, z, 0, 0, 0);
            s[t] = z;
        }
        // ---- causal mask + log2(ts) bias; per-row max ----
        float pm[4];
        #pragma unroll
        for (int r = 0; r < 4; r++) pm[r] = -1e30f;
        #pragma unroll
        for (int t = 0; t < 4; t++) {
            const int key = k0 + t * 16 + l16;
            const float lv = lt[key];
            #pragma unroll
            for (int r = 0; r < 4; r++) {
                float sv = (key <= qrow_my + r) ? (s[t][r] + lv) : -1e30f;
                s[t][r] = sv;
                pm[r] = fmaxf(pm[r], sv);
            }
        }
        #pragma unroll
        for (int r = 0; r < 4; r++) {     // reduce over 16 key-lanes
            float v = pm[r];
            v = fmaxf(v, __shfl_xor(v, 1));
            v = fmaxf(v, __shfl_xor(v, 2));
            v = fmaxf(v, __shfl_xor(v, 4));
            v = fmaxf(v, __shfl_xor(v, 8));
            float mnew = fmaxf(mrow[r], v);
            float sc = __builtin_amdgcn_exp2f(mrow[r] - mnew);
            mrow[r] = mnew;
            lrow[r] *= sc;
            o[0][r] *= sc; o[1][r] *= sc; o[2][r] *= sc; o[3][r] *= sc;
        }
        float rs[4] = {0.f, 0.f, 0.f, 0.f};
        #pragma unroll
        for (int t = 0; t < 4; t++)
            #pragma unroll
            for (int r = 0; r < 4; r++) {
                float p = __builtin_amdgcn_exp2f(s[t][r] - mrow[r]);
                s[t][r] = p;
                rs[r] += p;
            }
        #pragma unroll
        for (int r = 0; r < 4; r++) {
            float v = rs[r];
            v += __shfl_xor(v, 1);
            v += __shfl_xor(v, 2);
            v += __shfl_xor(v, 4);
            v += __shfl_xor(v, 8);
            lrow[r] += v;
        }
        // ---- P -> LDS (bf16), wave-private ----
        #pragma unroll
        for (int t = 0; t < 4; t++)
            #pragma unroll
            for (int r = 0; r < 4; r++)
                P[w][g*4 + r][t*16 + l16] = f2bf(s[t][r]);
        asm volatile("s_waitcnt lgkmcnt(0)" ::: "memory");
        // ---- O += P·V ----
        bf16x8 pa0 = ld_bf8(&P[w][l16][g*8]);
        bf16x8 pa1 = ld_bf8(&P[w][l16][32 + g*8]);
        #pragma unroll
        for (int j = 0; j < 4; j++) {
            const u16* vp = Vp + (size_t)(j*16 + l16) * 2048 + k0 + g*8;
            bf16x8 v0 = ld_bf8(vp);
            bf16x8 v1 = ld_bf8(vp + 32);
            o[j] = __builtin_amdgcn_mfma_f32_16x16x32_bf16(pa0, v0, o[j], 0, 0, 0);
            o[j] = __builtin_amdgcn_mfma_f32_16x16x32_bf16(pa1, v1, o[j], 0, 0, 0);
        }
    }
    // ---- normalize + write O[b][l][h*64+d] as bf16 ----
    float rl[4];
    #pragma unroll
    for (int r = 0; r < 4; r++) rl[r] = 1.f / lrow[r];
    #pragma unroll
    for (int j = 0; j < 4; j++)
        #pragma unroll
        for (int r = 0; r < 4; r++) {
            const int q = q0 + g*4 + r;
            O[((size_t)b*2048 + q)*768 + h*64 + j*16 + l16] = f2bf(o[j][r] * rl[r]);
        }
}

// ------------------------------------------------------------- k_merge ----
__global__ __launch_bounds__(256) void kmerge_kernel(
    const u16* __restrict__ Kb, float* __restrict__ out)
{
    const int idx = blockIdx.x * 256 + threadIdx.x;   // < 2*2048*64
    const int d = idx & 63, l = (idx >> 6) & 2047, b = idx >> 17;
    float s = 0.f;
    #pragma unroll
    for (int h = 0; h < 12; h++)
        s += bf2f(Kb[(((size_t)(b*12 + h))*2048 + l)*64 + d]);
    out[idx] = s * (1.f / 12.f);
}

// -------------------------------------------------------------- launch ----
extern "C" void kernel_launch(void* const* d_in, const int* in_sizes, int n_in,
                              void* d_out, int out_size, void* d_ws, size_t ws_size,
                              hipStream_t stream)
{
    const float* x     = (const float*)d_in[0];
    const float* ts    = (const float*)d_in[1];
    // d_in[2] = attn_mask (causal, hardcoded)
    const unsigned char* kpm = (const unsigned char*)d_in[3];
    const float* qkvw  = (const float*)d_in[4];
    const float* qkvb  = (const float*)d_in[5];
    const float* projw = (const float*)d_in[6];
    const float* projb = (const float*)d_in[7];
    float* out = (float*)d_out;

    char* ws = (char*)d_ws;
    u16* Xb = (u16*)ws;  ws += (size_t)4096 * 768 * 2;
    u16* Wq = (u16*)ws;  ws += (size_t)2304 * 768 * 2;
    u16* Wp = (u16*)ws;  ws += (size_t)768 * 768 * 2;
    u16* Qb = (u16*)ws;  ws += (size_t)24 * 2048 * 64 * 2;
    u16* Kb = (u16*)ws;  ws += (size_t)24 * 2048 * 64 * 2;
    u16* Vt = (u16*)ws;  ws += (size_t)24 * 2048 * 64 * 2;
    u16* Ob = (u16*)ws;  ws += (size_t)4096 * 768 * 2;
    float* logts = (float*)ws;

    const int prep_total = 4096*768 + 2304*768 + 768*768 + 2*2048;
    prep_kernel<<<(prep_total + 255) / 256, 256, 0, stream>>>(
        x, qkvw, projw, ts, kpm, Xb, Wq, Wp, logts);

    gemm_bt<0><<<dim3(18, 32), 256, 0, stream>>>(Xb, Wq, qkvb, Qb, Kb, Vt, nullptr);

    attn_kernel<<<dim3(32, 24), 256, 0, stream>>>(Qb, Kb, Vt, logts, Ob);

    kmerge_kernel<<<(2*2048*64) / 256, 256, 0, stream>>>(Kb, out + 3145728);

    gemm_bt<1><<<dim3(6, 32), 256, 0, stream>>>(Ob, Wp, projb, nullptr, nullptr, nullptr, out);
}